// Round 4
// baseline (131.644 us; speedup 1.0000x reference)
//
#include <hip/hip_runtime.h>
#include <hip/hip_bf16.h>
#include <cstdint>
#include <cstddef>

// ---- constants mirrored from the reference ----
#define LAM_S_F 0.7f
#define LAM_L_F 0.3f
#define ANCHOR_PAGES 4
#define FLOW_WINDOW 8
#define FLASH_TOP_K 32
#define QMAX 32
#define NEGF (-10000.0f)

__device__ __forceinline__ float wave_sum(float v) {
#pragma unroll
  for (int off = 32; off > 0; off >>= 1) v += __shfl_xor(v, off);
  return v;
}

// ---------------------------------------------------------------------------
// Kernel 1: one block per (b, n) page.
//  - semantic score: dot(q, k) / (max(||q||,eps) * max(||k||,eps))
//  - lexical score : sum of token weights where page_valid & token in q_ids
//  - page_valid.any(-1)
// 256 threads; Dp == 1024 -> one float4 per thread. P (=64) <= one wave.
// ---------------------------------------------------------------------------
__global__ __launch_bounds__(256) void qp_scores_kernel(
    const float* __restrict__ block_repr,
    const float* __restrict__ query_hidden,
    const int*   __restrict__ input_ids,
    const float* __restrict__ tok_w,
    const int*   __restrict__ query_start,
    const int*   __restrict__ query_end,
    const int*   __restrict__ page_valid,
    const int*   __restrict__ page_indices,
    const int*   __restrict__ token_valid,
    float* __restrict__ o_sem,
    float* __restrict__ o_lex,
    int*   __restrict__ o_pany,
    int N, int P, int Dp, int L)
{
  const int n   = blockIdx.x;
  const int b   = blockIdx.y;
  const int tid = threadIdx.x;

  __shared__ int   qids[QMAX];
  __shared__ float part[4][3];

  // q_ids for this batch (recomputed per block; all loads L1/L2-hot)
  if (tid < QMAX) {
    const int qsr = query_start[b], qer = query_end[b];
    const int qs = min(max(qsr, 0), L - 1);
    const int qe = min(max(qer, 0), L - 1);
    const int pos = min(qs + tid, L - 1);
    const bool m = (tid <= qe - qs) && (qer >= qsr) &&
                   (token_valid[(size_t)b * L + pos] != 0);
    qids[tid] = m ? input_ids[(size_t)b * L + pos] : -1;
  }

  // semantic partial sums (issue the big loads before the barrier)
  const float4 kv =
      reinterpret_cast<const float4*>(block_repr + ((size_t)b * N + n) * Dp)[tid];
  const float4 qv =
      reinterpret_cast<const float4*>(query_hidden + (size_t)b * Dp)[tid];
  float s_qk = kv.x * qv.x + kv.y * qv.y + kv.z * qv.z + kv.w * qv.w;
  float s_kk = kv.x * kv.x + kv.y * kv.y + kv.z * kv.z + kv.w * kv.w;
  float s_qq = qv.x * qv.x + qv.y * qv.y + qv.z * qv.z + qv.w * qv.w;

  __syncthreads();  // qids visible

  // lexical: one token per thread (P <= 64 -> wave 0 only)
  float lex = 0.f;
  bool  pv  = false;
  if (tid < P) {
    const size_t pbase = ((size_t)b * N + n) * (size_t)P + tid;
    const int   idx = page_indices[pbase];
    pv              = (page_valid[pbase] != 0);
    const int   tk  = input_ids[(size_t)b * L + idx];
    const float w   = tok_w[(size_t)b * L + idx];
    bool match = false;
#pragma unroll
    for (int q = 0; q < QMAX; ++q) match = match || (tk == qids[q]);
    lex = (pv && match) ? w : 0.f;
  }

  s_qk = wave_sum(s_qk);
  s_kk = wave_sum(s_kk);
  s_qq = wave_sum(s_qq);
  const int lane = tid & 63, wid = tid >> 6;
  if (lane == 0) { part[wid][0] = s_qk; part[wid][1] = s_kk; part[wid][2] = s_qq; }

  float lexs = 0.f;
  unsigned long long anyv = 0ull;
  if (wid == 0) {             // whole wave 0 participates
    lexs = wave_sum(lex);
    anyv = __ballot(pv);
  }
  __syncthreads();

  if (tid == 0) {
    const float S1 = part[0][0] + part[1][0] + part[2][0] + part[3][0];
    const float S2 = part[0][1] + part[1][1] + part[2][1] + part[3][1];
    const float S3 = part[0][2] + part[1][2] + part[2][2] + part[3][2];
    const float sem =
        S1 / (fmaxf(sqrtf(S3), 1e-12f) * fmaxf(sqrtf(S2), 1e-12f));
    const size_t o = (size_t)b * N + n;
    o_sem[o]  = sem;
    o_lex[o]  = lexs;
    o_pany[o] = (anyv != 0ull) ? 1 : 0;
  }
}

// ---------------------------------------------------------------------------
// Kernel 2: one block per batch, N threads (N=1024, 16 waves).
// masked min/max norm, anchor prefix-sum, flow window, single-wave top-32.
// Output written as int32 0/1 (reference output is bool -> int32 on harness).
// ---------------------------------------------------------------------------
__global__ __launch_bounds__(1024) void qp_select_kernel(
    const float* __restrict__ o_sem,
    const float* __restrict__ o_lex,
    const int*   __restrict__ o_pany,
    const int*   __restrict__ segment_ids,
    const int*   __restrict__ token2page,
    const int*   __restrict__ query_pos,
    int* __restrict__ out,
    int N, int L)
{
  const int b    = blockIdx.x;
  const int n    = threadIdx.x;
  const int lane = n & 63;
  const int wid  = n >> 6;
  const int NW   = blockDim.x >> 6;  // 16

  __shared__ float sc_arr[1024];
  __shared__ unsigned char fl_arr[1024];
  __shared__ float wred[16][4];
  __shared__ int   wcnt[16];
  __shared__ float g[4];

  const int qp = max(token2page[(size_t)b * L + (size_t)query_pos[b]], 0);
  const size_t o = (size_t)b * N + n;
  const float sem = o_sem[o];
  const float lex = o_lex[o];
  const int   seg = segment_ids[o];
  const bool  valid = (o_pany[o] != 0) && (seg >= 0) && (n <= qp);

  // masked min/max, 4 quantities, wave-level butterfly
  float smin = valid ? sem : INFINITY;
  float smax = valid ? sem : -INFINITY;
  float lmin = valid ? lex : INFINITY;
  float lmax = valid ? lex : -INFINITY;
#pragma unroll
  for (int off = 32; off > 0; off >>= 1) {
    smin = fminf(smin, __shfl_xor(smin, off));
    smax = fmaxf(smax, __shfl_xor(smax, off));
    lmin = fminf(lmin, __shfl_xor(lmin, off));
    lmax = fmaxf(lmax, __shfl_xor(lmax, off));
  }

  // anchor: inclusive prefix count of is_seg0 (ballot within wave + wave totals)
  const bool is0 = (seg == 0) && valid;
  const unsigned long long bal = __ballot(is0);
  const int excl = (int)__popcll(bal & ((1ull << lane) - 1ull));

  if (lane == 0) {
    wred[wid][0] = smin; wred[wid][1] = smax;
    wred[wid][2] = lmin; wred[wid][3] = lmax;
    wcnt[wid] = (int)__popcll(bal);
  }
  __syncthreads();

  if (n == 0) {
    float a = INFINITY, bmx = -INFINITY, c = INFINITY, d = -INFINITY;
    for (int w = 0; w < NW; ++w) {
      a   = fminf(a, wred[w][0]);
      bmx = fmaxf(bmx, wred[w][1]);
      c   = fminf(c, wred[w][2]);
      d   = fmaxf(d, wred[w][3]);
    }
    g[0] = a; g[1] = bmx; g[2] = c; g[3] = d;
  }
  int prior = 0;
  for (int w = 0; w < wid; ++w) prior += wcnt[w];
  __syncthreads();

  const int  cum    = prior + excl + (is0 ? 1 : 0);
  const bool anchor = is0 && (cum <= ANCHOR_PAGES);

  // min-max normalization (flat => 0), mixed score
  const float rng_s = g[1] - g[0];
  const float rng_l = g[3] - g[2];
  const float sem_n = (rng_s < 1e-6f) ? 0.f : (sem - g[0]) / rng_s;
  const float lex_n = (rng_l < 1e-6f) ? 0.f : (lex - g[2]) / rng_l;
  const float mix = (LAM_S_F * sem_n + LAM_L_F * lex_n) / (LAM_S_F + LAM_L_F);

  const int  lower = max(qp - FLOW_WINDOW, 0);
  const bool flow  = ((n >= lower) && (n <= qp) && valid) || (n == qp);
  const bool base_keep = anchor || flow;
  const bool cand = valid && !base_keep;

  sc_arr[n] = cand ? mix : NEGF;   // candidates always >= 0 > NEG
  fl_arr[n] = 0;
  __syncthreads();

  // single-wave top-32 (jax tie-break: equal value -> lower index)
  if (wid == 0) {
    float bestv = -INFINITY;
    int   besti = lane;
#pragma unroll
    for (int i = 0; i < 16; ++i) {
      const int idx = lane + (i << 6);
      const float v = sc_arr[idx];
      if (v > bestv) { bestv = v; besti = idx; }  // ascending idx + strict > => lowest idx on tie
    }
    for (int t = 0; t < FLASH_TOP_K; ++t) {
      float v = bestv;
      int   ix = besti;
#pragma unroll
      for (int off = 1; off < 64; off <<= 1) {
        const float ov  = __shfl_xor(v, off);
        const int   oix = __shfl_xor(ix, off);
        if (ov > v || (ov == v && oix < ix)) { v = ov; ix = oix; }
      }
      // all lanes agree on (v, ix)
      if (!(v > NEGF + 1.0f)) break;  // only non-candidates / removed left
      if ((ix & 63) == lane) {        // owner lane: flag, remove, rescan
        fl_arr[ix] = 1;
        sc_arr[ix] = -INFINITY;
        bestv = -INFINITY; besti = lane;
#pragma unroll
        for (int i = 0; i < 16; ++i) {
          const int idx = lane + (i << 6);
          const float vv = sc_arr[idx];
          if (vv > bestv) { bestv = vv; besti = idx; }
        }
      }
    }
  }
  __syncthreads();

  out[o] = (base_keep || (fl_arr[n] != 0)) ? 1 : 0;
}

// ---------------------------------------------------------------------------
extern "C" void kernel_launch(void* const* d_in, const int* in_sizes, int n_in,
                              void* d_out, int out_size, void* d_ws, size_t ws_size,
                              hipStream_t stream) {
  const float* block_repr   = (const float*)d_in[0];
  const float* query_hidden = (const float*)d_in[1];
  const int*   query_pos    = (const int*)d_in[2];
  const int*   input_ids    = (const int*)d_in[3];
  const float* tok_w        = (const float*)d_in[4];
  const int*   query_start  = (const int*)d_in[5];
  const int*   query_end    = (const int*)d_in[6];
  const int*   segment_ids  = (const int*)d_in[7];
  const int*   page_valid   = (const int*)d_in[8];
  const int*   page_indices = (const int*)d_in[9];
  const int*   token2page   = (const int*)d_in[10];
  const int*   token_valid  = (const int*)d_in[11];

  const int B  = in_sizes[2];            // query_pos: (B,)
  const int Dp = in_sizes[1] / B;        // query_hidden: (B, Dp)
  const int L  = in_sizes[3] / B;        // input_ids: (B, L)
  const int N  = in_sizes[7] / B;        // segment_ids: (B, N)
  const int P  = in_sizes[8] / (B * N);  // page_valid: (B, N, P)

  float* o_sem  = (float*)d_ws;
  float* o_lex  = o_sem + (size_t)B * N;
  int*   o_pany = (int*)(o_lex + (size_t)B * N);
  int*   out    = (int*)d_out;

  dim3 g1(N, B);
  qp_scores_kernel<<<g1, dim3(256), 0, stream>>>(
      block_repr, query_hidden, input_ids, tok_w, query_start, query_end,
      page_valid, page_indices, token_valid, o_sem, o_lex, o_pany, N, P, Dp, L);

  qp_select_kernel<<<dim3(B), dim3(N), 0, stream>>>(
      o_sem, o_lex, o_pany, segment_ids, token2page, query_pos, out, N, L);
}

// Round 5
// 125.699 us; speedup vs baseline: 1.0473x; 1.0473x over previous
//
#include <hip/hip_runtime.h>
#include <hip/hip_bf16.h>
#include <cstdint>
#include <cstddef>

// ---- constants mirrored from the reference ----
#define LAM_S_F 0.7f
#define LAM_L_F 0.3f
#define ANCHOR_PAGES 4
#define FLOW_WINDOW 8
#define FLASH_TOP_K 32
#define QMAX 32
#define NEGF (-10000.0f)

__device__ __forceinline__ float wave_sum(float v) {
#pragma unroll
  for (int off = 32; off > 0; off >>= 1) v += __shfl_xor(v, off);
  return v;
}

// ---------------------------------------------------------------------------
// Kernel 1: one block per (b, n) page.
// Pages with n > query_page can never be valid (valid_mask requires
// page_idx <= query_page) -> skip their 4KB block_repr read + gathers (~25%).
// ---------------------------------------------------------------------------
__global__ __launch_bounds__(256) void qp_scores_kernel(
    const float* __restrict__ block_repr,
    const float* __restrict__ query_hidden,
    const int*   __restrict__ input_ids,
    const float* __restrict__ tok_w,
    const int*   __restrict__ query_start,
    const int*   __restrict__ query_end,
    const int*   __restrict__ page_valid,
    const int*   __restrict__ page_indices,
    const int*   __restrict__ token_valid,
    const int*   __restrict__ token2page,
    const int*   __restrict__ query_pos,
    float* __restrict__ o_sem,
    float* __restrict__ o_lex,
    int*   __restrict__ o_pany,
    int N, int P, int Dp, int L)
{
  const int n   = blockIdx.x;
  const int b   = blockIdx.y;
  const int tid = threadIdx.x;

  // early-out: page can never be valid (wave-uniform branch, s_load chain L2-hot)
  const int qp = max(token2page[(size_t)b * L + (size_t)query_pos[b]], 0);
  if (n > qp) {
    if (tid == 0) {
      const size_t o = (size_t)b * N + n;
      o_sem[o] = 0.f; o_lex[o] = 0.f; o_pany[o] = 0;
    }
    return;
  }

  __shared__ int   qids[QMAX];
  __shared__ float part[4][3];

  // q_ids for this batch (recomputed per block; all loads L1/L2-hot)
  if (tid < QMAX) {
    const int qsr = query_start[b], qer = query_end[b];
    const int qs = min(max(qsr, 0), L - 1);
    const int qe = min(max(qer, 0), L - 1);
    const int pos = min(qs + tid, L - 1);
    const bool m = (tid <= qe - qs) && (qer >= qsr) &&
                   (token_valid[(size_t)b * L + pos] != 0);
    qids[tid] = m ? input_ids[(size_t)b * L + pos] : -1;
  }

  // semantic partial sums (issue the big loads before the barrier)
  const float4 kv =
      reinterpret_cast<const float4*>(block_repr + ((size_t)b * N + n) * Dp)[tid];
  const float4 qv =
      reinterpret_cast<const float4*>(query_hidden + (size_t)b * Dp)[tid];
  float s_qk = kv.x * qv.x + kv.y * qv.y + kv.z * qv.z + kv.w * qv.w;
  float s_kk = kv.x * kv.x + kv.y * kv.y + kv.z * kv.z + kv.w * kv.w;
  float s_qq = qv.x * qv.x + qv.y * qv.y + qv.z * qv.z + qv.w * qv.w;

  __syncthreads();  // qids visible

  // lexical: one token per thread (P <= 64 -> wave 0 only)
  float lex = 0.f;
  bool  pv  = false;
  if (tid < P) {
    const size_t pbase = ((size_t)b * N + n) * (size_t)P + tid;
    const int   idx = page_indices[pbase];
    pv              = (page_valid[pbase] != 0);
    const int   tk  = input_ids[(size_t)b * L + idx];
    const float w   = tok_w[(size_t)b * L + idx];
    bool match = false;
#pragma unroll
    for (int q = 0; q < QMAX; ++q) match = match || (tk == qids[q]);
    lex = (pv && match) ? w : 0.f;
  }

  s_qk = wave_sum(s_qk);
  s_kk = wave_sum(s_kk);
  s_qq = wave_sum(s_qq);
  const int lane = tid & 63, wid = tid >> 6;
  if (lane == 0) { part[wid][0] = s_qk; part[wid][1] = s_kk; part[wid][2] = s_qq; }

  float lexs = 0.f;
  unsigned long long anyv = 0ull;
  if (wid == 0) {             // whole wave 0 participates
    lexs = wave_sum(lex);
    anyv = __ballot(pv);
  }
  __syncthreads();

  if (tid == 0) {
    const float S1 = part[0][0] + part[1][0] + part[2][0] + part[3][0];
    const float S2 = part[0][1] + part[1][1] + part[2][1] + part[3][1];
    const float S3 = part[0][2] + part[1][2] + part[2][2] + part[3][2];
    const float sem =
        S1 / (fmaxf(sqrtf(S3), 1e-12f) * fmaxf(sqrtf(S2), 1e-12f));
    const size_t o = (size_t)b * N + n;
    o_sem[o]  = sem;
    o_lex[o]  = lexs;
    o_pany[o] = (anyv != 0ull) ? 1 : 0;
  }
}

// ---------------------------------------------------------------------------
// Kernel 2: one block per batch, N threads (N=1024, 16 waves).
// Top-32 via register-resident packed u64 keys in wave 0:
//   key = ((score_bits+1) << 10) | (1023 - n)   (0 = not a candidate)
// monotone in score (score >= 0), exact jax tie-break (lower index wins).
// ---------------------------------------------------------------------------
__global__ __launch_bounds__(1024) void qp_select_kernel(
    const float* __restrict__ o_sem,
    const float* __restrict__ o_lex,
    const int*   __restrict__ o_pany,
    const int*   __restrict__ segment_ids,
    const int*   __restrict__ token2page,
    const int*   __restrict__ query_pos,
    int* __restrict__ out,
    int N, int L)
{
  const int b    = blockIdx.x;
  const int n    = threadIdx.x;
  const int lane = n & 63;
  const int wid  = n >> 6;
  const int NW   = blockDim.x >> 6;  // 16

  __shared__ unsigned long long key_arr[1024];
  __shared__ unsigned char fl_arr[1024];
  __shared__ float wred[16][4];
  __shared__ int   wcnt[16];
  __shared__ float g[4];

  const int qp = max(token2page[(size_t)b * L + (size_t)query_pos[b]], 0);
  const size_t o = (size_t)b * N + n;
  const float sem = o_sem[o];
  const float lex = o_lex[o];
  const int   seg = segment_ids[o];
  const bool  valid = (o_pany[o] != 0) && (seg >= 0) && (n <= qp);

  // masked min/max, 4 quantities, wave-level butterfly
  float smin = valid ? sem : INFINITY;
  float smax = valid ? sem : -INFINITY;
  float lmin = valid ? lex : INFINITY;
  float lmax = valid ? lex : -INFINITY;
#pragma unroll
  for (int off = 32; off > 0; off >>= 1) {
    smin = fminf(smin, __shfl_xor(smin, off));
    smax = fmaxf(smax, __shfl_xor(smax, off));
    lmin = fminf(lmin, __shfl_xor(lmin, off));
    lmax = fmaxf(lmax, __shfl_xor(lmax, off));
  }

  // anchor: inclusive prefix count of is_seg0 (ballot within wave + wave totals)
  const bool is0 = (seg == 0) && valid;
  const unsigned long long bal = __ballot(is0);
  const int excl = (int)__popcll(bal & ((1ull << lane) - 1ull));

  if (lane == 0) {
    wred[wid][0] = smin; wred[wid][1] = smax;
    wred[wid][2] = lmin; wred[wid][3] = lmax;
    wcnt[wid] = (int)__popcll(bal);
  }
  __syncthreads();

  if (n == 0) {
    float a = INFINITY, bmx = -INFINITY, c = INFINITY, d = -INFINITY;
    for (int w = 0; w < NW; ++w) {
      a   = fminf(a, wred[w][0]);
      bmx = fmaxf(bmx, wred[w][1]);
      c   = fminf(c, wred[w][2]);
      d   = fmaxf(d, wred[w][3]);
    }
    g[0] = a; g[1] = bmx; g[2] = c; g[3] = d;
  }
  int prior = 0;
  for (int w = 0; w < wid; ++w) prior += wcnt[w];
  __syncthreads();

  const int  cum    = prior + excl + (is0 ? 1 : 0);
  const bool anchor = is0 && (cum <= ANCHOR_PAGES);

  // min-max normalization (flat => 0), mixed score
  const float rng_s = g[1] - g[0];
  const float rng_l = g[3] - g[2];
  const float sem_n = (rng_s < 1e-6f) ? 0.f : (sem - g[0]) / rng_s;
  const float lex_n = (rng_l < 1e-6f) ? 0.f : (lex - g[2]) / rng_l;
  const float mix = (LAM_S_F * sem_n + LAM_L_F * lex_n) / (LAM_S_F + LAM_L_F);

  const int  lower = max(qp - FLOW_WINDOW, 0);
  const bool flow  = ((n >= lower) && (n <= qp) && valid) || (n == qp);
  const bool base_keep = anchor || flow;
  const bool cand = valid && !base_keep;

  // packed sortable key (mix >= 0 for candidates -> float bits monotone)
  const unsigned int sb = __float_as_uint(mix);
  key_arr[n] = cand
      ? ((((unsigned long long)(sb + 1u)) << 10) | (unsigned long long)(1023 - n))
      : 0ull;
  fl_arr[n] = 0;
  __syncthreads();

  // single-wave top-32, all state in registers (static indexing only)
  if (wid == 0) {
    unsigned long long kk[16];
#pragma unroll
    for (int i = 0; i < 16; ++i) kk[i] = key_arr[lane + (i << 6)];
    for (int t = 0; t < FLASH_TOP_K; ++t) {
      unsigned long long lm = 0ull;
#pragma unroll
      for (int i = 0; i < 16; ++i) lm = (kk[i] > lm) ? kk[i] : lm;
#pragma unroll
      for (int off = 1; off < 64; off <<= 1) {
        const unsigned long long ov = __shfl_xor(lm, off);
        lm = (ov > lm) ? ov : lm;
      }
      if (lm == 0ull) break;  // no candidates remain (uniform across wave)
      const int win = 1023 - (int)(lm & 1023ull);
      if ((win & 63) == lane) {   // owner lane: flag + remove (static idx)
        fl_arr[win] = 1;
#pragma unroll
        for (int i = 0; i < 16; ++i) if (i == (win >> 6)) kk[i] = 0ull;
      }
    }
  }
  __syncthreads();

  out[o] = (base_keep || (fl_arr[n] != 0)) ? 1 : 0;
}

// ---------------------------------------------------------------------------
extern "C" void kernel_launch(void* const* d_in, const int* in_sizes, int n_in,
                              void* d_out, int out_size, void* d_ws, size_t ws_size,
                              hipStream_t stream) {
  const float* block_repr   = (const float*)d_in[0];
  const float* query_hidden = (const float*)d_in[1];
  const int*   query_pos    = (const int*)d_in[2];
  const int*   input_ids    = (const int*)d_in[3];
  const float* tok_w        = (const float*)d_in[4];
  const int*   query_start  = (const int*)d_in[5];
  const int*   query_end    = (const int*)d_in[6];
  const int*   segment_ids  = (const int*)d_in[7];
  const int*   page_valid   = (const int*)d_in[8];
  const int*   page_indices = (const int*)d_in[9];
  const int*   token2page   = (const int*)d_in[10];
  const int*   token_valid  = (const int*)d_in[11];

  const int B  = in_sizes[2];            // query_pos: (B,)
  const int Dp = in_sizes[1] / B;        // query_hidden: (B, Dp)
  const int L  = in_sizes[3] / B;        // input_ids: (B, L)
  const int N  = in_sizes[7] / B;        // segment_ids: (B, N)
  const int P  = in_sizes[8] / (B * N);  // page_valid: (B, N, P)

  float* o_sem  = (float*)d_ws;
  float* o_lex  = o_sem + (size_t)B * N;
  int*   o_pany = (int*)(o_lex + (size_t)B * N);
  int*   out    = (int*)d_out;

  dim3 g1(N, B);
  qp_scores_kernel<<<g1, dim3(256), 0, stream>>>(
      block_repr, query_hidden, input_ids, tok_w, query_start, query_end,
      page_valid, page_indices, token_valid, token2page, query_pos,
      o_sem, o_lex, o_pany, N, P, Dp, L);

  qp_select_kernel<<<dim3(B), dim3(N), 0, stream>>>(
      o_sem, o_lex, o_pany, segment_ids, token2page, query_pos, out, N, L);
}

// Round 6
// 123.421 us; speedup vs baseline: 1.0666x; 1.0185x over previous
//
#include <hip/hip_runtime.h>
#include <hip/hip_bf16.h>
#include <cstdint>
#include <cstddef>

// ---- constants mirrored from the reference ----
#define LAM_S_F 0.7f
#define LAM_L_F 0.3f
#define ANCHOR_PAGES 4
#define FLOW_WINDOW 8
#define FLASH_TOP_K 32
#define QMAX 32
#define NEGF (-10000.0f)

__device__ __forceinline__ float wave_sum(float v) {
#pragma unroll
  for (int off = 32; off > 0; off >>= 1) v += __shfl_xor(v, off);
  return v;
}

// ---------------------------------------------------------------------------
// Kernel 1: one WAVE per page (4 pages per 256-thread block).
//  - lane l holds k[16l..16l+16) and q[16l..16l+16): Dp=1024 = 64 lanes x 16.
//  - dot + norms: 3 wave-local butterflies, no LDS, no barrier.
//  - lexical: P=64 = wave width -> fully wave-local (ballot + wave_sum).
//  - single __syncthreads for the shared qids[32].
//  - pages with n > query_page can never be valid -> skip the 4KB read.
// ---------------------------------------------------------------------------
__global__ __launch_bounds__(256) void qp_scores_kernel(
    const float* __restrict__ block_repr,
    const float* __restrict__ query_hidden,
    const int*   __restrict__ input_ids,
    const float* __restrict__ tok_w,
    const int*   __restrict__ query_start,
    const int*   __restrict__ query_end,
    const int*   __restrict__ page_valid,
    const int*   __restrict__ page_indices,
    const int*   __restrict__ token_valid,
    const int*   __restrict__ token2page,
    const int*   __restrict__ query_pos,
    float* __restrict__ o_sem,
    float* __restrict__ o_lex,
    int*   __restrict__ o_pany,
    int N, int P, int Dp, int L)
{
  const int tid  = threadIdx.x;
  const int lane = tid & 63;
  const int wid  = tid >> 6;
  const int b    = blockIdx.y;
  const int n    = (blockIdx.x << 2) | wid;   // page owned by this wave

  __shared__ int qids[QMAX];

  const int qp = max(token2page[(size_t)b * L + (size_t)query_pos[b]], 0);
  const bool active = (n < N) && (n <= qp);

  // qids for this batch (one copy per block, shared by 4 waves)
  if (tid < QMAX) {
    const int qsr = query_start[b], qer = query_end[b];
    const int qs = min(max(qsr, 0), L - 1);
    const int qe = min(max(qer, 0), L - 1);
    const int pos = min(qs + tid, L - 1);
    const bool m = (tid <= qe - qs) && (qer >= qsr) &&
                   (token_valid[(size_t)b * L + pos] != 0);
    qids[tid] = m ? input_ids[(size_t)b * L + pos] : -1;
  }

  // semantic partial sums: 16 floats of k and q per lane (4x dwordx4 each)
  float s_qk = 0.f, s_kk = 0.f, s_qq = 0.f;
  if (active) {
    const float4* kb =
        reinterpret_cast<const float4*>(block_repr + ((size_t)b * N + n) * Dp);
    const float4* qb =
        reinterpret_cast<const float4*>(query_hidden + (size_t)b * Dp);
#pragma unroll
    for (int i = 0; i < 4; ++i) {
      const float4 kv = kb[(lane << 2) + i];
      const float4 qv = qb[(lane << 2) + i];
      s_qk += kv.x * qv.x + kv.y * qv.y + kv.z * qv.z + kv.w * qv.w;
      s_kk += kv.x * kv.x + kv.y * kv.y + kv.z * kv.z + kv.w * kv.w;
      s_qq += qv.x * qv.x + qv.y * qv.y + qv.z * qv.z + qv.w * qv.w;
    }
  }

  __syncthreads();  // qids visible to all 4 waves (all threads reach this)

  if (!active) {
    if (n < N && lane == 0) {
      const size_t o = (size_t)b * N + n;
      o_sem[o] = 0.f; o_lex[o] = 0.f; o_pany[o] = 0;
    }
    return;
  }

  // lexical: one token per lane (P == wave width)
  float lex = 0.f;
  bool  pv  = false;
  if (lane < P) {
    const size_t pbase = ((size_t)b * N + n) * (size_t)P + lane;
    const int   idx = page_indices[pbase];
    pv              = (page_valid[pbase] != 0);
    const int   tk  = input_ids[(size_t)b * L + idx];
    const float w   = tok_w[(size_t)b * L + idx];
    bool match = false;
#pragma unroll
    for (int q = 0; q < QMAX; ++q) match = match || (tk == qids[q]);
    lex = (pv && match) ? w : 0.f;
  }

  s_qk = wave_sum(s_qk);
  s_kk = wave_sum(s_kk);
  s_qq = wave_sum(s_qq);
  const float lexs = wave_sum(lex);
  const unsigned long long anyv = __ballot(pv);

  if (lane == 0) {
    const float sem =
        s_qk / (fmaxf(sqrtf(s_qq), 1e-12f) * fmaxf(sqrtf(s_kk), 1e-12f));
    const size_t o = (size_t)b * N + n;
    o_sem[o]  = sem;
    o_lex[o]  = lexs;
    o_pany[o] = (anyv != 0ull) ? 1 : 0;
  }
}

// ---------------------------------------------------------------------------
// Kernel 2: one block per batch, N threads (N=1024, 16 waves).
// Top-32 via register-resident packed u64 keys in wave 0:
//   key = ((score_bits+1) << 10) | (1023 - n)   (0 = not a candidate)
// monotone in score (score >= 0), exact jax tie-break (lower index wins).
// ---------------------------------------------------------------------------
__global__ __launch_bounds__(1024) void qp_select_kernel(
    const float* __restrict__ o_sem,
    const float* __restrict__ o_lex,
    const int*   __restrict__ o_pany,
    const int*   __restrict__ segment_ids,
    const int*   __restrict__ token2page,
    const int*   __restrict__ query_pos,
    int* __restrict__ out,
    int N, int L)
{
  const int b    = blockIdx.x;
  const int n    = threadIdx.x;
  const int lane = n & 63;
  const int wid  = n >> 6;
  const int NW   = blockDim.x >> 6;  // 16

  __shared__ unsigned long long key_arr[1024];
  __shared__ unsigned char fl_arr[1024];
  __shared__ float wred[16][4];
  __shared__ int   wcnt[16];
  __shared__ float g[4];

  const int qp = max(token2page[(size_t)b * L + (size_t)query_pos[b]], 0);
  const size_t o = (size_t)b * N + n;
  const float sem = o_sem[o];
  const float lex = o_lex[o];
  const int   seg = segment_ids[o];
  const bool  valid = (o_pany[o] != 0) && (seg >= 0) && (n <= qp);

  // masked min/max, 4 quantities, wave-level butterfly
  float smin = valid ? sem : INFINITY;
  float smax = valid ? sem : -INFINITY;
  float lmin = valid ? lex : INFINITY;
  float lmax = valid ? lex : -INFINITY;
#pragma unroll
  for (int off = 32; off > 0; off >>= 1) {
    smin = fminf(smin, __shfl_xor(smin, off));
    smax = fmaxf(smax, __shfl_xor(smax, off));
    lmin = fminf(lmin, __shfl_xor(lmin, off));
    lmax = fmaxf(lmax, __shfl_xor(lmax, off));
  }

  // anchor: inclusive prefix count of is_seg0 (ballot within wave + wave totals)
  const bool is0 = (seg == 0) && valid;
  const unsigned long long bal = __ballot(is0);
  const int excl = (int)__popcll(bal & ((1ull << lane) - 1ull));

  if (lane == 0) {
    wred[wid][0] = smin; wred[wid][1] = smax;
    wred[wid][2] = lmin; wred[wid][3] = lmax;
    wcnt[wid] = (int)__popcll(bal);
  }
  __syncthreads();

  if (n == 0) {
    float a = INFINITY, bmx = -INFINITY, c = INFINITY, d = -INFINITY;
    for (int w = 0; w < NW; ++w) {
      a   = fminf(a, wred[w][0]);
      bmx = fmaxf(bmx, wred[w][1]);
      c   = fminf(c, wred[w][2]);
      d   = fmaxf(d, wred[w][3]);
    }
    g[0] = a; g[1] = bmx; g[2] = c; g[3] = d;
  }
  int prior = 0;
  for (int w = 0; w < wid; ++w) prior += wcnt[w];
  __syncthreads();

  const int  cum    = prior + excl + (is0 ? 1 : 0);
  const bool anchor = is0 && (cum <= ANCHOR_PAGES);

  // min-max normalization (flat => 0), mixed score
  const float rng_s = g[1] - g[0];
  const float rng_l = g[3] - g[2];
  const float sem_n = (rng_s < 1e-6f) ? 0.f : (sem - g[0]) / rng_s;
  const float lex_n = (rng_l < 1e-6f) ? 0.f : (lex - g[2]) / rng_l;
  const float mix = (LAM_S_F * sem_n + LAM_L_F * lex_n) / (LAM_S_F + LAM_L_F);

  const int  lower = max(qp - FLOW_WINDOW, 0);
  const bool flow  = ((n >= lower) && (n <= qp) && valid) || (n == qp);
  const bool base_keep = anchor || flow;
  const bool cand = valid && !base_keep;

  // packed sortable key (mix >= 0 for candidates -> float bits monotone)
  const unsigned int sb = __float_as_uint(mix);
  key_arr[n] = cand
      ? ((((unsigned long long)(sb + 1u)) << 10) | (unsigned long long)(1023 - n))
      : 0ull;
  fl_arr[n] = 0;
  __syncthreads();

  // single-wave top-32, all state in registers (static indexing only)
  if (wid == 0) {
    unsigned long long kk[16];
#pragma unroll
    for (int i = 0; i < 16; ++i) kk[i] = key_arr[lane + (i << 6)];
    for (int t = 0; t < FLASH_TOP_K; ++t) {
      unsigned long long lm = 0ull;
#pragma unroll
      for (int i = 0; i < 16; ++i) lm = (kk[i] > lm) ? kk[i] : lm;
#pragma unroll
      for (int off = 1; off < 64; off <<= 1) {
        const unsigned long long ov = __shfl_xor(lm, off);
        lm = (ov > lm) ? ov : lm;
      }
      if (lm == 0ull) break;  // no candidates remain (uniform across wave)
      const int win = 1023 - (int)(lm & 1023ull);
      if ((win & 63) == lane) {   // owner lane: flag + remove (static idx)
        fl_arr[win] = 1;
#pragma unroll
        for (int i = 0; i < 16; ++i) if (i == (win >> 6)) kk[i] = 0ull;
      }
    }
  }
  __syncthreads();

  out[o] = (base_keep || (fl_arr[n] != 0)) ? 1 : 0;
}

// ---------------------------------------------------------------------------
extern "C" void kernel_launch(void* const* d_in, const int* in_sizes, int n_in,
                              void* d_out, int out_size, void* d_ws, size_t ws_size,
                              hipStream_t stream) {
  const float* block_repr   = (const float*)d_in[0];
  const float* query_hidden = (const float*)d_in[1];
  const int*   query_pos    = (const int*)d_in[2];
  const int*   input_ids    = (const int*)d_in[3];
  const float* tok_w        = (const float*)d_in[4];
  const int*   query_start  = (const int*)d_in[5];
  const int*   query_end    = (const int*)d_in[6];
  const int*   segment_ids  = (const int*)d_in[7];
  const int*   page_valid   = (const int*)d_in[8];
  const int*   page_indices = (const int*)d_in[9];
  const int*   token2page   = (const int*)d_in[10];
  const int*   token_valid  = (const int*)d_in[11];

  const int B  = in_sizes[2];            // query_pos: (B,)
  const int Dp = in_sizes[1] / B;        // query_hidden: (B, Dp)
  const int L  = in_sizes[3] / B;        // input_ids: (B, L)
  const int N  = in_sizes[7] / B;        // segment_ids: (B, N)
  const int P  = in_sizes[8] / (B * N);  // page_valid: (B, N, P)

  float* o_sem  = (float*)d_ws;
  float* o_lex  = o_sem + (size_t)B * N;
  int*   o_pany = (int*)(o_lex + (size_t)B * N);
  int*   out    = (int*)d_out;

  dim3 g1((N + 3) / 4, B);   // 4 pages (waves) per block
  qp_scores_kernel<<<g1, dim3(256), 0, stream>>>(
      block_repr, query_hidden, input_ids, tok_w, query_start, query_end,
      page_valid, page_indices, token_valid, token2page, query_pos,
      o_sem, o_lex, o_pany, N, P, Dp, L);

  qp_select_kernel<<<dim3(B), dim3(N), 0, stream>>>(
      o_sem, o_lex, o_pany, segment_ids, token2page, query_pos, out, N, L);
}